// Round 12
// baseline (46.735 us; speedup 1.0000x reference)
//
#include <hip/hip_runtime.h>
#include <stdint.h>

typedef int v4i  __attribute__((ext_vector_type(4)));
typedef int v16i __attribute__((ext_vector_type(16)));

// ---------------- ws layout (u32 indices) ----------------
#define W1P   0      // 18  per channel: wt25 | M<<25
#define INV1  18     // 1
#define CFP   20     // 84 floats: B1[18] S1[18] T1[18] B5[10] S5[10] T5[10]
#define THRW  104    // 48 ints: D = 450-2*M2  (stage-2 dot-space threshold)
#define INVM  152    // 2 words: inv mask ch0..31, ch32..47
#define B2I   160    // 12800: i8 B [25 ks][64 oc][32B], coalesced; oc>=48 zero
#define W3P   12960  // 120 o x 40 words (25 full + 13 hi16-pairs + 2 pad)
#define M3P   17760  // 120  M | inv<<11
#define FW1P  17880  // 252 o x 4 words
#define M4P   18888  // 252  M | inv<<7
#define FW2P  19140  // 80
// total 19220 words

__device__ inline bool negv(int dot, float B, float S, float T) {
  float v = __fadd_rn((float)dot, B);
  v = __fmul_rn(v, S);
  v = __fadd_rn(v, T);
  return v < 0.0f;
}

// neg-set over m (mismatch, dot = tot-2m) is affine-monotone: neg(m) == ((m >= M) ^ inv)
__device__ inline void scanMT(float B, float S, float T, int tot, int& M, int& inv) {
  bool b0 = negv(tot, B, S, T);
  bool be = negv(-tot, B, S, T);
  if (b0 == be) { M = 0; inv = b0 ? 0 : 1; return; }
  int lo = 0, hi = tot;
  while (hi - lo > 1) {
    int mid = (lo + hi) >> 1;
    if (negv(tot - 2*mid, B, S, T) == b0) lo = mid; else hi = mid;
  }
  M = hi; inv = b0 ? 1 : 0;
}

__device__ inline float bnS(float g, float v) {
  return __fdiv_rn(g, __fsqrt_rn(__fadd_rn(v, 1e-5f)));
}
__device__ inline float bnT(float be, float m, float s) {
  return __fsub_rn(be, __fmul_rn(m, s));
}

__global__ __launch_bounds__(256) void pack_kernel(
    const float* __restrict__ w1, const float* __restrict__ w2, const float* __restrict__ w3,
    const float* __restrict__ fw1, const float* __restrict__ fw2,
    const float* __restrict__ cb1, const float* __restrict__ g1, const float* __restrict__ be1,
    const float* __restrict__ m1, const float* __restrict__ v1,
    const float* __restrict__ cb2, const float* __restrict__ g2, const float* __restrict__ be2,
    const float* __restrict__ m2, const float* __restrict__ v2,
    const float* __restrict__ cb3, const float* __restrict__ g3, const float* __restrict__ be3,
    const float* __restrict__ m3, const float* __restrict__ v3,
    const float* __restrict__ fb1, const float* __restrict__ g4, const float* __restrict__ be4,
    const float* __restrict__ m4, const float* __restrict__ v4,
    const float* __restrict__ fb2, const float* __restrict__ g5, const float* __restrict__ be5,
    const float* __restrict__ m5, const float* __restrict__ v5,
    uint32_t* __restrict__ wsu)
{
  const int tid = blockIdx.x * 256 + threadIdx.x;

  if (tid < 18) {                         // w1 packed 25-bit + M
    int c = tid;
    uint32_t wt = 0;
    for (int ky = 0; ky < 5; ++ky)
      for (int kx = 0; kx < 5; ++kx)
        if (w1[c*25 + ky*5 + kx] < 0.0f) wt |= 1u << (ky*5 + kx);
    float S = bnS(g1[c], v1[c]);
    float B = cb1[c];
    float T = bnT(be1[c], m1[c], S);
    int M, iv; scanMT(B, S, T, 25, M, iv);
    wsu[W1P + c] = wt | ((uint32_t)M << 25);
  } else if (tid == 18) {                 // inv mask for stage1
    uint32_t mask = 0;
    for (int c = 0; c < 18; ++c) {
      float S = bnS(g1[c], v1[c]);
      float B = cb1[c];
      float T = bnT(be1[c], m1[c], S);
      int M, iv; scanMT(B, S, T, 25, M, iv);
      if (iv) mask |= 1u << c;
    }
    wsu[INV1] = mask;
  } else if (tid >= 20 && tid < 104) {    // CF floats
    int j = tid - 20;
    float outv;
    if (j < 18) outv = cb1[j];
    else if (j < 36) { int c = j - 18; outv = bnS(g1[c], v1[c]); }
    else if (j < 54) { int c = j - 36; float s = bnS(g1[c], v1[c]); outv = bnT(be1[c], m1[c], s); }
    else if (j < 64) { int c = j - 54; outv = fb2[c]; }
    else if (j < 74) { int c = j - 64; outv = bnS(g5[c], v5[c]); }
    else             { int c = j - 74; float s = bnS(g5[c], v5[c]); outv = bnT(be5[c], m5[c], s); }
    wsu[CFP + j] = __float_as_uint(outv);
  } else if (tid >= 128 && tid < 192) {   // stage-2 thresholds (one full wave: ballot)
    int o = tid - 128;
    bool inv = false;
    if (o < 48) {
      float S = bnS(g2[o], v2[o]);
      float B = cb2[o];
      float T = bnT(be2[o], m2[o], S);
      int M, iv; scanMT(B, S, T, 450, M, iv);
      wsu[THRW + o] = (uint32_t)(450 - 2*M);
      inv = (iv != 0);
    }
    unsigned long long bb = __ballot(inv);
    if (o == 0) {
      wsu[INVM]     = (uint32_t)bb;
      wsu[INVM + 1] = (uint32_t)(bb >> 32) & 0xFFFFu;
    }
  } else if (tid >= 256 && tid < 13056) { // B2I: [25 ks][64 slots][32B], coalesced
    int idx = tid - 256;                  // word index
    int ks   = idx >> 9;                  // 512 words per k-step
    int slot = (idx >> 3) & 63;
    int w4   = idx & 7;
    uint32_t d = 0;
    if (slot < 48) {
      #pragma unroll
      for (int j = 0; j < 4; ++j) {
        int c = w4*4 + j;
        uint32_t byte = 0;
        if (c < 18) byte = (w2[(slot*18 + c)*25 + ks] < 0.0f) ? 0xFFu : 0x01u;
        d |= byte << (8*j);
      }
    }
    wsu[B2I + idx] = d;
  } else if (tid >= 13056 && tid < 17856) { // W3 packed [120][40]
    int idx = tid - 13056;
    int o = idx / 40, wj = idx - o*40;
    uint32_t b = 0;
    if (wj < 25) {
      int p = wj;
      for (int c = 0; c < 32; ++c)
        if (w3[(o*48 + c)*25 + p] < 0.0f) b |= 1u << c;
    } else if (wj < 38) {
      int j = wj - 25;
      int p0 = 2*j, p1 = 2*j + 1;
      for (int q = 0; q < 16; ++q) {
        int c = 32 + q;
        if (w3[(o*48 + c)*25 + p0] < 0.0f) b |= 1u << q;
        if (p1 < 25 && w3[(o*48 + c)*25 + p1] < 0.0f) b |= 1u << (16 + q);
      }
    }
    wsu[W3P + idx] = b;
  } else if (tid >= 17856 && tid < 17976) { // M3
    int o = tid - 17856;
    float S = bnS(g3[o], v3[o]);
    float B = cb3[o];
    float T = bnT(be3[o], m3[o], S);
    int M, iv; scanMT(B, S, T, 1200, M, iv);
    wsu[M3P + o] = (uint32_t)M | ((uint32_t)iv << 11);
  } else if (tid >= 17976 && tid < 18984) { // fw1 [o][4]
    int idx = tid - 17976;
    int o = idx >> 2, wi = idx & 3;
    uint32_t b = 0;
    for (int j = 0; j < 32; ++j) {
      int col = wi*32 + j;
      if (col < 120 && fw1[o*120 + col] < 0.0f) b |= 1u << j;
    }
    wsu[FW1P + idx] = b;
  } else if (tid >= 18984 && tid < 19236) { // M4
    int o = tid - 18984;
    float S = bnS(g4[o], v4[o]);
    float B = fb1[o];
    float T = bnT(be4[o], m4[o], S);
    int M, iv; scanMT(B, S, T, 120, M, iv);
    wsu[M4P + o] = (uint32_t)M | ((uint32_t)iv << 7);
  } else if (tid >= 19236 && tid < 19316) { // fw2 [wi*10+o]
    int i = tid - 19236;
    int wi = i / 10, o = i - wi*10;
    uint32_t b = 0;
    for (int j = 0; j < 32; ++j) {
      int col = wi*32 + j;
      if (col < 252 && fw2[o*252 + col] < 0.0f) b |= 1u << j;
    }
    wsu[FW2P + i] = b;
  }
}

#define NIMG 2

__global__ __launch_bounds__(512, 6) void lenet_main(
    const float* __restrict__ x, const uint32_t* __restrict__ wsu,
    float* __restrict__ out)
{
  __shared__ __align__(16) uint8_t Alds[NIMG][196*32];  // i8 act, parity-swizzled
  __shared__ uint32_t xng[NIMG][32], xnz[NIMG][32];
  __shared__ __align__(16) uint32_t h2p[NIMG][40];
  __shared__ uint32_t h3s[NIMG][4];
  __shared__ uint32_t h4s[NIMG][8];
  __shared__ int      sthr[48];
  __shared__ uint32_t lut[16];
  __shared__ int      znz[NIMG][4];

  const int t = threadIdx.x;
  const int it = t & 255;          // thread within image team
  const int im = t >> 8;           // image slot 0/1
  const int lane = t & 63;         // hw lane
  const int wv = it >> 6;          // wave within image team (0-3)
  const int img = blockIdx.x * NIMG + im;

  // ---- input pack: it -> (row = it>>3, quad k = it&7), 4 px each ----
  {
    const float* xim = x + (size_t)img * 1024;
    const int row = it >> 3, k = it & 7;
    const float4 f = ((const float4*)(xim + row*32))[k];
    const uint32_t u0 = __float_as_uint(f.x), u1 = __float_as_uint(f.y),
                   u2 = __float_as_uint(f.z), u3 = __float_as_uint(f.w);
    uint32_t ng4 = (u0>>31) | ((u1>>31)<<1) | ((u2>>31)<<2) | ((u3>>31)<<3);
    uint32_t nz4 = (uint32_t)((u0<<1)!=0u) | ((uint32_t)((u1<<1)!=0u)<<1)
                 | ((uint32_t)((u2<<1)!=0u)<<2) | ((uint32_t)((u3<<1)!=0u)<<3);
    const bool tok = (nz4 == 0xFu);
    uint32_t ng = ng4 << (4*k), nz = nz4 << (4*k);
    ng |= __shfl_xor(ng, 1);  nz |= __shfl_xor(nz, 1);
    ng |= __shfl_xor(ng, 2);  nz |= __shfl_xor(nz, 2);
    ng |= __shfl_xor(ng, 4);  nz |= __shfl_xor(nz, 4);
    if (k == 0) { xng[im][row] = ng; xnz[im][row] = nz; }
    const int wok = __all(tok);
    if (lane == 0) znz[im][wv] = wok;
  }

  if (t < 16) {
    uint32_t v = 0;
    #pragma unroll
    for (int b = 0; b < 4; ++b) v |= (((t >> b) & 1) ? 0xFFu : 0x01u) << (8*b);
    lut[t] = v;
  }
  if (it < 40) h2p[im][it] = 0;
  if (t >= 64 && t < 112) sthr[t - 64] = (int)wsu[THRW + (t - 64)];
  __syncthreads();

  // ---- stage 1: conv1 + pool + threshold, expand to i8 A in LDS ----
  const bool zer = !(znz[im][0] & znz[im][1] & znz[im][2] & znz[im][3]);
  if (it < 196) {
    const int py = it / 14, px = it - py*14;
    const int x0 = 2*px, y0 = 2*py;
    uint32_t hm = 0;
    if (!zer) {
      const uint32_t a0 = xng[im][y0+0] >> x0, a1 = xng[im][y0+1] >> x0,
                     a2 = xng[im][y0+2] >> x0, a3 = xng[im][y0+3] >> x0,
                     a4 = xng[im][y0+4] >> x0, a5 = xng[im][y0+5] >> x0;
      const uint32_t w00 = (a0&31u) | ((a1&31u)<<5) | ((a2&31u)<<10) | ((a3&31u)<<15) | ((a4&31u)<<20);
      const uint32_t w01 = ((a0>>1)&31u) | (((a1>>1)&31u)<<5) | (((a2>>1)&31u)<<10) | (((a3>>1)&31u)<<15) | (((a4>>1)&31u)<<20);
      const uint32_t w10 = (a1&31u) | ((a2&31u)<<5) | ((a3&31u)<<10) | ((a4&31u)<<15) | ((a5&31u)<<20);
      const uint32_t w11 = ((a1>>1)&31u) | (((a2>>1)&31u)<<5) | (((a3>>1)&31u)<<10) | (((a4>>1)&31u)<<15) | (((a5>>1)&31u)<<20);
      const uint32_t iv1 = wsu[INV1];
      #pragma unroll
      for (int c = 0; c < 18; ++c) {
        const uint32_t wd = wsu[W1P + c];
        const uint32_t wt = wd & 0x1FFFFFFu;
        const int M = (int)(wd >> 25);
        const int mn = min(min(__popc(w00^wt), __popc(w01^wt)),
                           min(__popc(w10^wt), __popc(w11^wt)));
        hm |= (mn >= M) ? (1u << c) : 0u;
      }
      hm ^= iv1;
    } else {                              // exact-zero-aware float path (rare)
      uint32_t an[6], az[6];
      #pragma unroll
      for (int r6 = 0; r6 < 6; ++r6) { an[r6] = xng[im][y0+r6] >> x0; az[r6] = xnz[im][y0+r6] >> x0; }
      for (int c = 0; c < 18; ++c) {
        const uint32_t wt = wsu[W1P + c] & 0x1FFFFFFu;
        const float B = __uint_as_float(wsu[CFP + c]);
        const float S = __uint_as_float(wsu[CFP + 18 + c]);
        const float T = __uint_as_float(wsu[CFP + 36 + c]);
        int best = -1000;
        #pragma unroll
        for (int dy = 0; dy < 2; ++dy)
          #pragma unroll
          for (int dx = 0; dx < 2; ++dx) {
            int cnt = 0, ng = 0;
            #pragma unroll
            for (int k = 0; k < 5; ++k) {
              const uint32_t nzr = (az[dy+k] >> dx) & 31u;
              const uint32_t sgr = (an[dy+k] >> dx) & 31u;
              const uint32_t wr  = (wt >> (5*k)) & 31u;
              cnt += __popc(nzr);
              ng  += __popc((sgr ^ wr) & nzr);
            }
            const int conv = cnt - 2*ng;
            best = best > conv ? best : conv;
          }
        if (negv(best, B, S, T)) hm |= 1u << c;
      }
    }
    // expand 18 bits -> 32 i8 (c>=18 zero), halves swapped by pixel parity
    const uint32_t d0 = lut[hm & 15u];
    const uint32_t d1 = lut[(hm >> 4) & 15u];
    const uint32_t d2 = lut[(hm >> 8) & 15u];
    const uint32_t d3 = lut[(hm >> 12) & 15u];
    const uint32_t d4 = lut[(hm >> 16) & 15u] & 0x0000FFFFu;
    const int swz = (it & 1) << 4;
    uint8_t* ap = &Alds[im][it*32];
    *(uint2*)(ap + swz)            = make_uint2(d0, d1);
    *(uint2*)(ap + swz + 8)        = make_uint2(d2, d3);
    *(uint2*)(ap + (swz ^ 16))     = make_uint2(d4, 0u);
    *(uint2*)(ap + (swz ^ 16) + 8) = make_uint2(0u, 0u);
  }
  __syncthreads();

  // ---- stage 2: conv2 as i8 MFMA; A from LDS, B from global (L1/L2) ----
  {
    const int rl = lane & 31, kh = lane >> 5;
    const int q   = (wv << 3) + (rl >> 2);
    const int qc  = q < 24 ? q : 24;           // clamp for in-bounds addresses
    const int wnd = rl & 3;
    const int py = qc / 5, px = qc - py*5;
    const int Y0 = 2*py + (wnd >> 1), X0 = 2*px + (wnd & 1);
    const uint32_t pbase = (uint32_t)((Y0*14 + X0) * 32);
    const uint32_t aeven = pbase + (uint32_t)(((kh ^ (X0 & 1)) & 1) << 4);
    const uint32_t aodd  = aeven ^ 16u;
    const uint8_t* bg = (const uint8_t*)(wsu + B2I) + (rl*32 + kh*16);

    v16i acc0 = {};
    v16i acc1 = {};
    #pragma unroll
    for (int ks = 0; ks < 25; ++ks) {
      const int ky = ks / 5, kx = ks - (ks/5)*5;
      const uint32_t aoff = (uint32_t)((ky*14 + kx) * 32);
      v4i a  = *(const v4i*)(&Alds[im][((kx & 1) ? aodd : aeven) + aoff]);
      v4i b0 = *(const v4i*)(bg + ks*2048);
      v4i b1 = *(const v4i*)(bg + ks*2048 + 1024);
      acc0 = __builtin_amdgcn_mfma_i32_32x32x32_i8(a, b0, acc0, 0, 0, 0);
      acc1 = __builtin_amdgcn_mfma_i32_32x32x32_i8(a, b1, acc1, 0, 0, 0);
    }

    const int D0 = sthr[rl];
    const int D1 = sthr[rl + 32 < 47 ? rl + 32 : 47];
    const uint32_t ivm0 = wsu[INVM];
    const uint32_t ivm1d = (wsu[INVM + 1] & 0xFFFFu) * 0x10001u;
    #pragma unroll
    for (int g = 0; g < 4; ++g) {
      const int p0 = max(max(acc0[4*g], acc0[4*g+1]), max(acc0[4*g+2], acc0[4*g+3]));
      const int p1 = max(max(acc1[4*g], acc1[4*g+1]), max(acc1[4*g+2], acc1[4*g+3]));
      unsigned long long e0 = __ballot(p0 <= D0);
      unsigned long long e1 = __ballot(p1 <= D1);
      if (lane == 0) {
        const int pool = (wv << 3) + 2*g;
        if (pool < 25) {
          h2p[im][pool] = (uint32_t)e0 ^ ivm0;
          uint32_t hw = ((uint32_t)e1 & 0xFFFFu) | (((uint32_t)(e1 >> 32) & 0xFFFFu) << 16);
          hw ^= ivm1d;
          if (pool + 1 < 25) h2p[im][pool + 1] = (uint32_t)(e0 >> 32) ^ ivm0;
          else hw &= 0xFFFFu;
          h2p[im][25 + (pool >> 1)] = hw;
        }
      }
    }
  }
  __syncthreads();

  // ---- stage 3: conv3 (48->120), 240 thr/image = (o, half), shfl combine ----
  {
    bool pred = false;
    if (it < 240) {
      const int o = it >> 1, h = it & 1;
      const uint4* wp = (const uint4*)(wsu + W3P + o*40 + h*20);
      const uint32_t* hv = &h2p[im][h*20];
      int mm = 0;
      #pragma unroll
      for (int qq = 0; qq < 5; ++qq) {
        const uint4 ww = wp[qq];
        mm += __popc(hv[qq*4+0] ^ ww.x) + __popc(hv[qq*4+1] ^ ww.y)
            + __popc(hv[qq*4+2] ^ ww.z) + __popc(hv[qq*4+3] ^ ww.w);
      }
      mm += __shfl_xor(mm, 1);
      const uint32_t mw = wsu[M3P + o];
      pred = (((mm >= (int)(mw & 2047u)) ? 1u : 0u) ^ (mw >> 11)) != 0u;
    }
    unsigned long long bb = __ballot(pred && ((it & 1) == 0));
    unsigned long long xq = bb & 0x5555555555555555ull;
    xq = (xq | (xq >> 1))  & 0x3333333333333333ull;
    xq = (xq | (xq >> 2))  & 0x0F0F0F0F0F0F0F0Full;
    xq = (xq | (xq >> 4))  & 0x00FF00FF00FF00FFull;
    xq = (xq | (xq >> 8))  & 0x0000FFFF0000FFFFull;
    xq = (xq | (xq >> 16)) & 0x00000000FFFFFFFFull;
    if (lane == 0) h3s[im][wv] = (uint32_t)xq;
  }
  __syncthreads();

  // ---- stage 4: fc1 (120->252), ballot -> h4 bits (252 thr/image) ----
  {
    bool pred = false;
    if (it < 252) {
      const uint4 fr = ((const uint4*)(wsu + FW1P))[it];
      const int mm = __popc(h3s[im][0] ^ fr.x) + __popc(h3s[im][1] ^ fr.y)
                   + __popc(h3s[im][2] ^ fr.z) + __popc(h3s[im][3] ^ fr.w);
      const uint32_t mw = wsu[M4P + it];
      pred = (((mm >= (int)(mw & 127u)) ? 1u : 0u) ^ (mw >> 7)) != 0u;
    }
    unsigned long long bb = __ballot(pred);
    if (lane == 0) {
      h4s[im][wv*2]   = (uint32_t)bb;
      h4s[im][wv*2+1] = (uint32_t)(bb >> 32);
    }
  }
  __syncthreads();

  // ---- stage 5: fc2 + bn + log_softmax (16 lanes per image) ----
  if (it < 16) {
    float vv = -1e30f;
    if (it < 10) {
      int mm = 0;
      #pragma unroll
      for (int wi = 0; wi < 8; ++wi)
        mm += __popc(h4s[im][wi] ^ wsu[FW2P + wi*10 + it]);
      const int dot = 252 - 2*mm;
      const float B = __uint_as_float(wsu[CFP + 54 + it]);
      const float S = __uint_as_float(wsu[CFP + 64 + it]);
      const float T = __uint_as_float(wsu[CFP + 74 + it]);
      float v = __fadd_rn((float)dot, B);
      v = __fmul_rn(v, S);
      vv = __fadd_rn(v, T);
    }
    float mx = vv;
    #pragma unroll
    for (int d = 1; d < 16; d <<= 1)
      mx = fmaxf(mx, __shfl_xor(mx, d, 16));
    const float sh = __fsub_rn(vv, mx);
    float s = expf(sh);
    #pragma unroll
    for (int d = 1; d < 16; d <<= 1)
      s = __fadd_rn(s, __shfl_xor(s, d, 16));
    if (it < 10)
      out[(size_t)img*10 + it] = __fsub_rn(sh, logf(s));
  }
}

extern "C" void kernel_launch(void* const* d_in, const int* in_sizes, int n_in,
                              void* d_out, int out_size, void* d_ws, size_t ws_size,
                              hipStream_t stream)
{
  const float* x   = (const float*)d_in[0];
  const float* w1  = (const float*)d_in[1];
  const float* cb1 = (const float*)d_in[2];
  const float* g1  = (const float*)d_in[3];
  const float* be1 = (const float*)d_in[4];
  const float* m1  = (const float*)d_in[5];
  const float* v1  = (const float*)d_in[6];
  const float* w2  = (const float*)d_in[7];
  const float* cb2 = (const float*)d_in[8];
  const float* g2  = (const float*)d_in[9];
  const float* be2 = (const float*)d_in[10];
  const float* m2  = (const float*)d_in[11];
  const float* v2  = (const float*)d_in[12];
  const float* w3  = (const float*)d_in[13];
  const float* cb3 = (const float*)d_in[14];
  const float* g3  = (const float*)d_in[15];
  const float* be3 = (const float*)d_in[16];
  const float* m3  = (const float*)d_in[17];
  const float* v3  = (const float*)d_in[18];
  const float* fw1 = (const float*)d_in[19];
  const float* fb1 = (const float*)d_in[20];
  const float* g4  = (const float*)d_in[21];
  const float* be4 = (const float*)d_in[22];
  const float* m4  = (const float*)d_in[23];
  const float* v4  = (const float*)d_in[24];
  const float* fw2 = (const float*)d_in[25];
  const float* fb2 = (const float*)d_in[26];
  const float* g5  = (const float*)d_in[27];
  const float* be5 = (const float*)d_in[28];
  const float* m5  = (const float*)d_in[29];
  const float* v5  = (const float*)d_in[30];

  uint32_t* wsu = (uint32_t*)d_ws;
  float* out = (float*)d_out;

  hipLaunchKernelGGL(pack_kernel, dim3(76), dim3(256), 0, stream,
                     w1, w2, w3, fw1, fw2,
                     cb1, g1, be1, m1, v1,
                     cb2, g2, be2, m2, v2,
                     cb3, g3, be3, m3, v3,
                     fb1, g4, be4, m4, v4,
                     fb2, g5, be5, m5, v5,
                     wsu);

  hipLaunchKernelGGL(lenet_main, dim3(2048), dim3(512), 0, stream,
                     x, wsu, out);
}

// Round 13
// 43.184 us; speedup vs baseline: 1.0822x; 1.0822x over previous
//
#include <hip/hip_runtime.h>
#include <stdint.h>

typedef int v4i  __attribute__((ext_vector_type(4)));
typedef int v16i __attribute__((ext_vector_type(16)));

// ---------------- ws layout (u32 indices) ----------------
#define W1P   0      // 18  per channel: wt25 | M<<25
#define INV1  18     // 1
#define CFP   20     // 84 floats: B1[18] S1[18] T1[18] B5[10] S5[10] T5[10]
#define THRW  104    // 48 ints: D = 450-2*M2  (stage-2 dot-space threshold)
#define INVM  152    // 2 words: inv mask ch0..31, ch32..47
#define B2I   160    // 9792: i8 B^T [48][816B], word-XOR-swizzled by ((o>>3)&1)<<2
#define W3P   9952   // 120 o x 40 words (25 full + 13 hi16-pairs + 2 pad)
#define M3P   14752  // 120  M | inv<<11
#define FW1P  14872  // 252 o x 4 words
#define M4P   15880  // 252  M | inv<<7
#define FW2P  16132  // 80
// total 16212 words

__device__ inline bool negv(int dot, float B, float S, float T) {
  float v = __fadd_rn((float)dot, B);
  v = __fmul_rn(v, S);
  v = __fadd_rn(v, T);
  return v < 0.0f;
}

// neg-set over m (mismatch, dot = tot-2m) is affine-monotone: neg(m) == ((m >= M) ^ inv)
__device__ inline void scanMT(float B, float S, float T, int tot, int& M, int& inv) {
  bool b0 = negv(tot, B, S, T);
  bool be = negv(-tot, B, S, T);
  if (b0 == be) { M = 0; inv = b0 ? 0 : 1; return; }
  int lo = 0, hi = tot;
  while (hi - lo > 1) {
    int mid = (lo + hi) >> 1;
    if (negv(tot - 2*mid, B, S, T) == b0) lo = mid; else hi = mid;
  }
  M = hi; inv = b0 ? 1 : 0;
}

__device__ inline float bnS(float g, float v) {
  return __fdiv_rn(g, __fsqrt_rn(__fadd_rn(v, 1e-5f)));
}
__device__ inline float bnT(float be, float m, float s) {
  return __fsub_rn(be, __fmul_rn(m, s));
}

__global__ __launch_bounds__(256) void pack_kernel(
    const float* __restrict__ w1, const float* __restrict__ w2, const float* __restrict__ w3,
    const float* __restrict__ fw1, const float* __restrict__ fw2,
    const float* __restrict__ cb1, const float* __restrict__ g1, const float* __restrict__ be1,
    const float* __restrict__ m1, const float* __restrict__ v1,
    const float* __restrict__ cb2, const float* __restrict__ g2, const float* __restrict__ be2,
    const float* __restrict__ m2, const float* __restrict__ v2,
    const float* __restrict__ cb3, const float* __restrict__ g3, const float* __restrict__ be3,
    const float* __restrict__ m3, const float* __restrict__ v3,
    const float* __restrict__ fb1, const float* __restrict__ g4, const float* __restrict__ be4,
    const float* __restrict__ m4, const float* __restrict__ v4,
    const float* __restrict__ fb2, const float* __restrict__ g5, const float* __restrict__ be5,
    const float* __restrict__ m5, const float* __restrict__ v5,
    uint32_t* __restrict__ wsu)
{
  const int tid = blockIdx.x * 256 + threadIdx.x;

  if (tid < 18) {                         // w1 packed 25-bit + M
    int c = tid;
    uint32_t wt = 0;
    for (int ky = 0; ky < 5; ++ky)
      for (int kx = 0; kx < 5; ++kx)
        if (w1[c*25 + ky*5 + kx] < 0.0f) wt |= 1u << (ky*5 + kx);
    float S = bnS(g1[c], v1[c]);
    float B = cb1[c];
    float T = bnT(be1[c], m1[c], S);
    int M, iv; scanMT(B, S, T, 25, M, iv);
    wsu[W1P + c] = wt | ((uint32_t)M << 25);
  } else if (tid == 18) {                 // inv mask for stage1
    uint32_t mask = 0;
    for (int c = 0; c < 18; ++c) {
      float S = bnS(g1[c], v1[c]);
      float B = cb1[c];
      float T = bnT(be1[c], m1[c], S);
      int M, iv; scanMT(B, S, T, 25, M, iv);
      if (iv) mask |= 1u << c;
    }
    wsu[INV1] = mask;
  } else if (tid >= 20 && tid < 104) {    // CF floats
    int j = tid - 20;
    float outv;
    if (j < 18) outv = cb1[j];
    else if (j < 36) { int c = j - 18; outv = bnS(g1[c], v1[c]); }
    else if (j < 54) { int c = j - 36; float s = bnS(g1[c], v1[c]); outv = bnT(be1[c], m1[c], s); }
    else if (j < 64) { int c = j - 54; outv = fb2[c]; }
    else if (j < 74) { int c = j - 64; outv = bnS(g5[c], v5[c]); }
    else             { int c = j - 74; float s = bnS(g5[c], v5[c]); outv = bnT(be5[c], m5[c], s); }
    wsu[CFP + j] = __float_as_uint(outv);
  } else if (tid >= 128 && tid < 192) {   // stage-2 thresholds (one full wave: ballot)
    int o = tid - 128;
    bool inv = false;
    if (o < 48) {
      float S = bnS(g2[o], v2[o]);
      float B = cb2[o];
      float T = bnT(be2[o], m2[o], S);
      int M, iv; scanMT(B, S, T, 450, M, iv);
      wsu[THRW + o] = (uint32_t)(450 - 2*M);
      inv = (iv != 0);
    }
    unsigned long long bb = __ballot(inv);
    if (o == 0) {
      wsu[INVM]     = (uint32_t)bb;
      wsu[INVM + 1] = (uint32_t)(bb >> 32) & 0xFFFFu;
    }
  } else if (tid >= 256 && tid < 10048) { // B2I: i8 B^T [48][816], bank-swizzled
    int idx = tid - 256;
    int o = idx / 204, rem = idx - o*204;
    int k4 = rem * 4;
    uint32_t d = 0;
    if (k4 < 800) {
      int tap = k4 >> 5, cb = k4 & 31;
      #pragma unroll
      for (int j = 0; j < 4; ++j) {
        int c = cb + j;
        uint32_t byte = 0;
        if (c < 18) byte = (w2[(o*18 + c)*25 + tap] < 0.0f) ? 0xFFu : 0x01u;
        d |= byte << (8*j);
      }
    }
    wsu[B2I + (idx ^ (((o >> 3) & 1) << 2))] = d;
  } else if (tid >= 10048 && tid < 14848) { // W3 packed [120][40]
    int idx = tid - 10048;
    int o = idx / 40, wj = idx - o*40;
    uint32_t b = 0;
    if (wj < 25) {
      int p = wj;
      for (int c = 0; c < 32; ++c)
        if (w3[(o*48 + c)*25 + p] < 0.0f) b |= 1u << c;
    } else if (wj < 38) {
      int j = wj - 25;
      int p0 = 2*j, p1 = 2*j + 1;
      for (int q = 0; q < 16; ++q) {
        int c = 32 + q;
        if (w3[(o*48 + c)*25 + p0] < 0.0f) b |= 1u << q;
        if (p1 < 25 && w3[(o*48 + c)*25 + p1] < 0.0f) b |= 1u << (16 + q);
      }
    }
    wsu[W3P + idx] = b;
  } else if (tid >= 14848 && tid < 14968) { // M3
    int o = tid - 14848;
    float S = bnS(g3[o], v3[o]);
    float B = cb3[o];
    float T = bnT(be3[o], m3[o], S);
    int M, iv; scanMT(B, S, T, 1200, M, iv);
    wsu[M3P + o] = (uint32_t)M | ((uint32_t)iv << 11);
  } else if (tid >= 15104 && tid < 16112) { // fw1 [o][4]
    int idx = tid - 15104;
    int o = idx >> 2, wi = idx & 3;
    uint32_t b = 0;
    for (int j = 0; j < 32; ++j) {
      int col = wi*32 + j;
      if (col < 120 && fw1[o*120 + col] < 0.0f) b |= 1u << j;
    }
    wsu[FW1P + idx] = b;
  } else if (tid >= 16128 && tid < 16380) { // M4
    int o = tid - 16128;
    float S = bnS(g4[o], v4[o]);
    float B = fb1[o];
    float T = bnT(be4[o], m4[o], S);
    int M, iv; scanMT(B, S, T, 120, M, iv);
    wsu[M4P + o] = (uint32_t)M | ((uint32_t)iv << 7);
  } else if (tid >= 16384 && tid < 16464) { // fw2 [wi*10+o]
    int i = tid - 16384;
    int wi = i / 10, o = i - wi*10;
    uint32_t b = 0;
    for (int j = 0; j < 32; ++j) {
      int col = wi*32 + j;
      if (col < 252 && fw2[o*252 + col] < 0.0f) b |= 1u << j;
    }
    wsu[FW2P + i] = b;
  }
}

#define NIMG 2

__global__ __launch_bounds__(512, 6) void lenet_main(
    const float* __restrict__ x, const uint32_t* __restrict__ wsu,
    float* __restrict__ out)
{
  __shared__ __align__(16) uint8_t Blds[48*816];        // shared across images
  __shared__ __align__(16) uint8_t Alds[NIMG][196*32];  // i8 act, parity-swizzled
  __shared__ uint32_t xng[NIMG][32], xnz[NIMG][32];
  __shared__ __align__(16) uint32_t h2p[NIMG][40];
  __shared__ uint32_t h3s[NIMG][4];
  __shared__ uint32_t h4s[NIMG][8];
  __shared__ int      sthr[48];
  __shared__ uint32_t lut[16];
  __shared__ int      znz[NIMG][4];

  const int t = threadIdx.x;
  const int it = t & 255;          // thread within image team
  const int im = t >> 8;           // image slot 0/1
  const int lane = t & 63;         // hw lane
  const int wv = it >> 6;          // wave within image team (0-3)
  const int img = blockIdx.x * NIMG + im;

  // ---- issue B loads first (global -> regs, in flight under the pack) ----
  uint4 breg[5];
  {
    const uint4* bsrc = (const uint4*)(wsu + B2I);
    #pragma unroll
    for (int i = 0; i < 5; ++i) {
      int idx = t + i*512;
      breg[i] = (idx < 2448) ? bsrc[idx] : make_uint4(0u,0u,0u,0u);
    }
  }

  // ---- input pack: it -> (row = it>>3, quad k = it&7), 4 px each ----
  {
    const float* xim = x + (size_t)img * 1024;
    const int row = it >> 3, k = it & 7;
    const float4 f = ((const float4*)(xim + row*32))[k];
    const uint32_t u0 = __float_as_uint(f.x), u1 = __float_as_uint(f.y),
                   u2 = __float_as_uint(f.z), u3 = __float_as_uint(f.w);
    uint32_t ng4 = (u0>>31) | ((u1>>31)<<1) | ((u2>>31)<<2) | ((u3>>31)<<3);
    uint32_t nz4 = (uint32_t)((u0<<1)!=0u) | ((uint32_t)((u1<<1)!=0u)<<1)
                 | ((uint32_t)((u2<<1)!=0u)<<2) | ((uint32_t)((u3<<1)!=0u)<<3);
    const bool tok = (nz4 == 0xFu);
    uint32_t ng = ng4 << (4*k), nz = nz4 << (4*k);
    ng |= __shfl_xor(ng, 1);  nz |= __shfl_xor(nz, 1);
    ng |= __shfl_xor(ng, 2);  nz |= __shfl_xor(nz, 2);
    ng |= __shfl_xor(ng, 4);  nz |= __shfl_xor(nz, 4);
    if (k == 0) { xng[im][row] = ng; xnz[im][row] = nz; }
    const int wok = __all(tok);
    if (lane == 0) znz[im][wv] = wok;
  }

  if (t < 16) {
    uint32_t v = 0;
    #pragma unroll
    for (int b = 0; b < 4; ++b) v |= (((t >> b) & 1) ? 0xFFu : 0x01u) << (8*b);
    lut[t] = v;
  }
  if (it < 40) h2p[im][it] = 0;
  if (t >= 64 && t < 112) sthr[t - 64] = (int)wsu[THRW + (t - 64)];

  // ---- drain B into LDS ----
  {
    uint4* bdst = (uint4*)Blds;
    #pragma unroll
    for (int i = 0; i < 5; ++i) {
      int idx = t + i*512;
      if (idx < 2448) bdst[idx] = breg[i];
    }
  }
  __syncthreads();

  // ---- stage 1: conv1 + pool + threshold, expand to i8 A in LDS ----
  const bool zer = !(znz[im][0] & znz[im][1] & znz[im][2] & znz[im][3]);
  if (it < 196) {
    const int py = it / 14, px = it - py*14;
    const int x0 = 2*px, y0 = 2*py;
    uint32_t hm = 0;
    if (!zer) {
      const uint32_t a0 = xng[im][y0+0] >> x0, a1 = xng[im][y0+1] >> x0,
                     a2 = xng[im][y0+2] >> x0, a3 = xng[im][y0+3] >> x0,
                     a4 = xng[im][y0+4] >> x0, a5 = xng[im][y0+5] >> x0;
      const uint32_t w00 = (a0&31u) | ((a1&31u)<<5) | ((a2&31u)<<10) | ((a3&31u)<<15) | ((a4&31u)<<20);
      const uint32_t w01 = ((a0>>1)&31u) | (((a1>>1)&31u)<<5) | (((a2>>1)&31u)<<10) | (((a3>>1)&31u)<<15) | (((a4>>1)&31u)<<20);
      const uint32_t w10 = (a1&31u) | ((a2&31u)<<5) | ((a3&31u)<<10) | ((a4&31u)<<15) | ((a5&31u)<<20);
      const uint32_t w11 = ((a1>>1)&31u) | (((a2>>1)&31u)<<5) | (((a3>>1)&31u)<<10) | (((a4>>1)&31u)<<15) | (((a5>>1)&31u)<<20);
      const uint32_t iv1 = wsu[INV1];
      #pragma unroll
      for (int c = 0; c < 18; ++c) {
        const uint32_t wd = wsu[W1P + c];
        const uint32_t wt = wd & 0x1FFFFFFu;
        const int M = (int)(wd >> 25);
        const int mn = min(min(__popc(w00^wt), __popc(w01^wt)),
                           min(__popc(w10^wt), __popc(w11^wt)));
        hm |= (mn >= M) ? (1u << c) : 0u;
      }
      hm ^= iv1;
    } else {                              // exact-zero-aware float path (rare)
      uint32_t an[6], az[6];
      #pragma unroll
      for (int r6 = 0; r6 < 6; ++r6) { an[r6] = xng[im][y0+r6] >> x0; az[r6] = xnz[im][y0+r6] >> x0; }
      for (int c = 0; c < 18; ++c) {
        const uint32_t wt = wsu[W1P + c] & 0x1FFFFFFu;
        const float B = __uint_as_float(wsu[CFP + c]);
        const float S = __uint_as_float(wsu[CFP + 18 + c]);
        const float T = __uint_as_float(wsu[CFP + 36 + c]);
        int best = -1000;
        #pragma unroll
        for (int dy = 0; dy < 2; ++dy)
          #pragma unroll
          for (int dx = 0; dx < 2; ++dx) {
            int cnt = 0, ng = 0;
            #pragma unroll
            for (int k = 0; k < 5; ++k) {
              const uint32_t nzr = (az[dy+k] >> dx) & 31u;
              const uint32_t sgr = (an[dy+k] >> dx) & 31u;
              const uint32_t wr  = (wt >> (5*k)) & 31u;
              cnt += __popc(nzr);
              ng  += __popc((sgr ^ wr) & nzr);
            }
            const int conv = cnt - 2*ng;
            best = best > conv ? best : conv;
          }
        if (negv(best, B, S, T)) hm |= 1u << c;
      }
    }
    // expand 18 bits -> 32 i8 (c>=18 zero), halves swapped by pixel parity
    const uint32_t d0 = lut[hm & 15u];
    const uint32_t d1 = lut[(hm >> 4) & 15u];
    const uint32_t d2 = lut[(hm >> 8) & 15u];
    const uint32_t d3 = lut[(hm >> 12) & 15u];
    const uint32_t d4 = lut[(hm >> 16) & 15u] & 0x0000FFFFu;
    const int swz = (it & 1) << 4;
    uint8_t* ap = &Alds[im][it*32];
    *(uint2*)(ap + swz)            = make_uint2(d0, d1);
    *(uint2*)(ap + swz + 8)        = make_uint2(d2, d3);
    *(uint2*)(ap + (swz ^ 16))     = make_uint2(d4, 0u);
    *(uint2*)(ap + (swz ^ 16) + 8) = make_uint2(0u, 0u);
  }
  __syncthreads();

  // ---- stage 2: conv2 as i8 MFMA (M=128 pool-major, N=64, K=800) ----
  {
    const int rl = lane & 31, kh = lane >> 5;
    const int q   = (wv << 3) + (rl >> 2);
    const int qc  = q < 24 ? q : 24;           // clamp for in-bounds addresses
    const int wnd = rl & 3;
    const int py = qc / 5, px = qc - py*5;
    const int Y0 = 2*py + (wnd >> 1), X0 = 2*px + (wnd & 1);
    const uint32_t pbase = (uint32_t)((Y0*14 + X0) * 32);
    const uint32_t aeven = pbase + (uint32_t)(((kh ^ (X0 & 1)) & 1) << 4);
    const uint32_t aodd  = aeven ^ 16u;
    const int oc0 = rl;
    const int oc1 = rl + 32 < 47 ? rl + 32 : 47;
    const uint8_t* bbase0 = Blds + (((uint32_t)(oc0*816 + (kh << 4))) ^ ((uint32_t)((oc0 >> 3) & 1) << 4));
    const uint8_t* bbase1 = Blds + (((uint32_t)(oc1*816 + (kh << 4))) ^ ((uint32_t)((oc1 >> 3) & 1) << 4));

    v16i acc0 = {};
    v16i acc1 = {};
    __builtin_amdgcn_s_setprio(1);
    #pragma unroll
    for (int ks = 0; ks < 25; ++ks) {
      const int ky = ks / 5, kx = ks - (ks/5)*5;
      const uint32_t aoff = (uint32_t)((ky*14 + kx) * 32);
      v4i a  = *(const v4i*)(&Alds[im][((kx & 1) ? aodd : aeven) + aoff]);
      v4i b0 = *(const v4i*)(bbase0 + ks*32);
      v4i b1 = *(const v4i*)(bbase1 + ks*32);
      acc0 = __builtin_amdgcn_mfma_i32_32x32x32_i8(a, b0, acc0, 0, 0, 0);
      acc1 = __builtin_amdgcn_mfma_i32_32x32x32_i8(a, b1, acc1, 0, 0, 0);
    }
    __builtin_amdgcn_s_setprio(0);

    const int D0 = sthr[oc0];
    const int D1 = sthr[oc1];
    const uint32_t ivm0 = wsu[INVM];
    const uint32_t ivm1d = (wsu[INVM + 1] & 0xFFFFu) * 0x10001u;
    #pragma unroll
    for (int g = 0; g < 4; ++g) {
      const int p0 = max(max(acc0[4*g], acc0[4*g+1]), max(acc0[4*g+2], acc0[4*g+3]));
      const int p1 = max(max(acc1[4*g], acc1[4*g+1]), max(acc1[4*g+2], acc1[4*g+3]));
      unsigned long long e0 = __ballot(p0 <= D0);
      unsigned long long e1 = __ballot(p1 <= D1);
      if (lane == 0) {
        const int pool = (wv << 3) + 2*g;
        if (pool < 25) {
          h2p[im][pool] = (uint32_t)e0 ^ ivm0;
          uint32_t hw = ((uint32_t)e1 & 0xFFFFu) | (((uint32_t)(e1 >> 32) & 0xFFFFu) << 16);
          hw ^= ivm1d;
          if (pool + 1 < 25) h2p[im][pool + 1] = (uint32_t)(e0 >> 32) ^ ivm0;
          else hw &= 0xFFFFu;
          h2p[im][25 + (pool >> 1)] = hw;
        }
      }
    }
  }
  __syncthreads();

  // ---- stage 3: conv3 (48->120), 240 thr/image = (o, half), shfl combine ----
  {
    bool pred = false;
    if (it < 240) {
      const int o = it >> 1, h = it & 1;
      const uint4* wp = (const uint4*)(wsu + W3P + o*40 + h*20);
      const uint32_t* hv = &h2p[im][h*20];
      int mm = 0;
      #pragma unroll
      for (int qq = 0; qq < 5; ++qq) {
        const uint4 ww = wp[qq];
        mm += __popc(hv[qq*4+0] ^ ww.x) + __popc(hv[qq*4+1] ^ ww.y)
            + __popc(hv[qq*4+2] ^ ww.z) + __popc(hv[qq*4+3] ^ ww.w);
      }
      mm += __shfl_xor(mm, 1);
      const uint32_t mw = wsu[M3P + o];
      pred = (((mm >= (int)(mw & 2047u)) ? 1u : 0u) ^ (mw >> 11)) != 0u;
    }
    unsigned long long bb = __ballot(pred && ((it & 1) == 0));
    unsigned long long xq = bb & 0x5555555555555555ull;
    xq = (xq | (xq >> 1))  & 0x3333333333333333ull;
    xq = (xq | (xq >> 2))  & 0x0F0F0F0F0F0F0F0Full;
    xq = (xq | (xq >> 4))  & 0x00FF00FF00FF00FFull;
    xq = (xq | (xq >> 8))  & 0x0000FFFF0000FFFFull;
    xq = (xq | (xq >> 16)) & 0x00000000FFFFFFFFull;
    if (lane == 0) h3s[im][wv] = (uint32_t)xq;
  }
  __syncthreads();

  // ---- stage 4: fc1 (120->252), ballot -> h4 bits (252 thr/image) ----
  {
    bool pred = false;
    if (it < 252) {
      const uint4 fr = ((const uint4*)(wsu + FW1P))[it];
      const int mm = __popc(h3s[im][0] ^ fr.x) + __popc(h3s[im][1] ^ fr.y)
                   + __popc(h3s[im][2] ^ fr.z) + __popc(h3s[im][3] ^ fr.w);
      const uint32_t mw = wsu[M4P + it];
      pred = (((mm >= (int)(mw & 127u)) ? 1u : 0u) ^ (mw >> 7)) != 0u;
    }
    unsigned long long bb = __ballot(pred);
    if (lane == 0) {
      h4s[im][wv*2]   = (uint32_t)bb;
      h4s[im][wv*2+1] = (uint32_t)(bb >> 32);
    }
  }
  __syncthreads();

  // ---- stage 5: fc2 + bn + log_softmax (16 lanes per image) ----
  if (it < 16) {
    float vv = -1e30f;
    if (it < 10) {
      int mm = 0;
      #pragma unroll
      for (int wi = 0; wi < 8; ++wi)
        mm += __popc(h4s[im][wi] ^ wsu[FW2P + wi*10 + it]);
      const int dot = 252 - 2*mm;
      const float B = __uint_as_float(wsu[CFP + 54 + it]);
      const float S = __uint_as_float(wsu[CFP + 64 + it]);
      const float T = __uint_as_float(wsu[CFP + 74 + it]);
      float v = __fadd_rn((float)dot, B);
      v = __fmul_rn(v, S);
      vv = __fadd_rn(v, T);
    }
    float mx = vv;
    #pragma unroll
    for (int d = 1; d < 16; d <<= 1)
      mx = fmaxf(mx, __shfl_xor(mx, d, 16));
    const float sh = __fsub_rn(vv, mx);
    float s = expf(sh);
    #pragma unroll
    for (int d = 1; d < 16; d <<= 1)
      s = __fadd_rn(s, __shfl_xor(s, d, 16));
    if (it < 10)
      out[(size_t)img*10 + it] = __fsub_rn(sh, logf(s));
  }
}

extern "C" void kernel_launch(void* const* d_in, const int* in_sizes, int n_in,
                              void* d_out, int out_size, void* d_ws, size_t ws_size,
                              hipStream_t stream)
{
  const float* x   = (const float*)d_in[0];
  const float* w1  = (const float*)d_in[1];
  const float* cb1 = (const float*)d_in[2];
  const float* g1  = (const float*)d_in[3];
  const float* be1 = (const float*)d_in[4];
  const float* m1  = (const float*)d_in[5];
  const float* v1  = (const float*)d_in[6];
  const float* w2  = (const float*)d_in[7];
  const float* cb2 = (const float*)d_in[8];
  const float* g2  = (const float*)d_in[9];
  const float* be2 = (const float*)d_in[10];
  const float* m2  = (const float*)d_in[11];
  const float* v2  = (const float*)d_in[12];
  const float* w3  = (const float*)d_in[13];
  const float* cb3 = (const float*)d_in[14];
  const float* g3  = (const float*)d_in[15];
  const float* be3 = (const float*)d_in[16];
  const float* m3  = (const float*)d_in[17];
  const float* v3  = (const float*)d_in[18];
  const float* fw1 = (const float*)d_in[19];
  const float* fb1 = (const float*)d_in[20];
  const float* g4  = (const float*)d_in[21];
  const float* be4 = (const float*)d_in[22];
  const float* m4  = (const float*)d_in[23];
  const float* v4  = (const float*)d_in[24];
  const float* fw2 = (const float*)d_in[25];
  const float* fb2 = (const float*)d_in[26];
  const float* g5  = (const float*)d_in[27];
  const float* be5 = (const float*)d_in[28];
  const float* m5  = (const float*)d_in[29];
  const float* v5  = (const float*)d_in[30];

  uint32_t* wsu = (uint32_t*)d_ws;
  float* out = (float*)d_out;

  hipLaunchKernelGGL(pack_kernel, dim3(65), dim3(256), 0, stream,
                     w1, w2, w3, fw1, fw2,
                     cb1, g1, be1, m1, v1,
                     cb2, g2, be2, m2, v2,
                     cb3, g3, be3, m3, v3,
                     fb1, g4, be4, m4, v4,
                     fb2, g5, be5, m5, v5,
                     wsu);

  hipLaunchKernelGGL(lenet_main, dim3(2048), dim3(512), 0, stream,
                     x, wsu, out);
}

// Round 14
// 36.163 us; speedup vs baseline: 1.2923x; 1.1942x over previous
//
#include <hip/hip_runtime.h>
#include <stdint.h>

typedef int v4i  __attribute__((ext_vector_type(4)));
typedef int v16i __attribute__((ext_vector_type(16)));

// ---------------- ws layout (u32 indices) ----------------
#define W1P   0      // 18  per channel: wt25 | M<<25
#define INV1  18     // 1
#define CFP   20     // 84 floats: B1[18] S1[18] T1[18] B5[10] S5[10] T5[10]
#define THRW  104    // 48 ints: D = 450-2*M2
#define INVM  152    // 2 words
#define B2I   160    // 7680: i8 B dense [15 slice][64 slot][32B]; slot>=48 or pad g>=90 -> 0
#define W3P   7840   // 120 o x 40 words
#define M3P   12640  // 120
#define FW1P  12760  // 1008
#define M4P   13768  // 252
#define FW2P  14020  // 80
// total 14100 words

__device__ inline bool negv(int dot, float B, float S, float T) {
  float v = __fadd_rn((float)dot, B);
  v = __fmul_rn(v, S);
  v = __fadd_rn(v, T);
  return v < 0.0f;
}

__device__ inline void scanMT(float B, float S, float T, int tot, int& M, int& inv) {
  bool b0 = negv(tot, B, S, T);
  bool be = negv(-tot, B, S, T);
  if (b0 == be) { M = 0; inv = b0 ? 0 : 1; return; }
  int lo = 0, hi = tot;
  while (hi - lo > 1) {
    int mid = (lo + hi) >> 1;
    if (negv(tot - 2*mid, B, S, T) == b0) lo = mid; else hi = mid;
  }
  M = hi; inv = b0 ? 1 : 0;
}

__device__ inline float bnS(float g, float v) {
  return __fdiv_rn(g, __fsqrt_rn(__fadd_rn(v, 1e-5f)));
}
__device__ inline float bnT(float be, float m, float s) {
  return __fsub_rn(be, __fmul_rn(m, s));
}

__global__ __launch_bounds__(256) void pack_kernel(
    const float* __restrict__ w1, const float* __restrict__ w2, const float* __restrict__ w3,
    const float* __restrict__ fw1, const float* __restrict__ fw2,
    const float* __restrict__ cb1, const float* __restrict__ g1, const float* __restrict__ be1,
    const float* __restrict__ m1, const float* __restrict__ v1,
    const float* __restrict__ cb2, const float* __restrict__ g2, const float* __restrict__ be2,
    const float* __restrict__ m2, const float* __restrict__ v2,
    const float* __restrict__ cb3, const float* __restrict__ g3, const float* __restrict__ be3,
    const float* __restrict__ m3, const float* __restrict__ v3,
    const float* __restrict__ fb1, const float* __restrict__ g4, const float* __restrict__ be4,
    const float* __restrict__ m4, const float* __restrict__ v4,
    const float* __restrict__ fb2, const float* __restrict__ g5, const float* __restrict__ be5,
    const float* __restrict__ m5, const float* __restrict__ v5,
    uint32_t* __restrict__ wsu)
{
  const int tid = blockIdx.x * 256 + threadIdx.x;

  if (tid < 18) {                         // w1 packed 25-bit + M
    int c = tid;
    uint32_t wt = 0;
    for (int ky = 0; ky < 5; ++ky)
      for (int kx = 0; kx < 5; ++kx)
        if (w1[c*25 + ky*5 + kx] < 0.0f) wt |= 1u << (ky*5 + kx);
    float S = bnS(g1[c], v1[c]);
    float B = cb1[c];
    float T = bnT(be1[c], m1[c], S);
    int M, iv; scanMT(B, S, T, 25, M, iv);
    wsu[W1P + c] = wt | ((uint32_t)M << 25);
  } else if (tid == 18) {                 // inv mask for stage1
    uint32_t mask = 0;
    for (int c = 0; c < 18; ++c) {
      float S = bnS(g1[c], v1[c]);
      float B = cb1[c];
      float T = bnT(be1[c], m1[c], S);
      int M, iv; scanMT(B, S, T, 25, M, iv);
      if (iv) mask |= 1u << c;
    }
    wsu[INV1] = mask;
  } else if (tid >= 20 && tid < 104) {    // CF floats
    int j = tid - 20;
    float outv;
    if (j < 18) outv = cb1[j];
    else if (j < 36) { int c = j - 18; outv = bnS(g1[c], v1[c]); }
    else if (j < 54) { int c = j - 36; float s = bnS(g1[c], v1[c]); outv = bnT(be1[c], m1[c], s); }
    else if (j < 64) { int c = j - 54; outv = fb2[c]; }
    else if (j < 74) { int c = j - 64; outv = bnS(g5[c], v5[c]); }
    else             { int c = j - 74; float s = bnS(g5[c], v5[c]); outv = bnT(be5[c], m5[c], s); }
    wsu[CFP + j] = __float_as_uint(outv);
  } else if (tid >= 128 && tid < 192) {   // stage-2 thresholds
    int o = tid - 128;
    bool inv = false;
    if (o < 48) {
      float S = bnS(g2[o], v2[o]);
      float B = cb2[o];
      float T = bnT(be2[o], m2[o], S);
      int M, iv; scanMT(B, S, T, 450, M, iv);
      wsu[THRW + o] = (uint32_t)(450 - 2*M);
      inv = (iv != 0);
    }
    unsigned long long bb = __ballot(inv);
    if (o == 0) {
      wsu[INVM]     = (uint32_t)bb;
      wsu[INVM + 1] = (uint32_t)(bb >> 32) & 0xFFFFu;
    }
  } else if (tid >= 256 && tid < 7936) {  // B2I dense: [15][64 slots][32B]
    int idx = tid - 256;                  // word index 0..7679
    int s    = idx >> 9;                  // slice 0..14
    int slot = (idx >> 3) & 63;
    int w4   = idx & 7;
    int ky = s / 3, part = s - 3*(s/3);
    uint32_t d = 0;
    if (slot < 48) {
      #pragma unroll
      for (int j = 0; j < 4; ++j) {
        int g = part*32 + w4*4 + j;       // byte within 96B row-segment
        uint32_t byte = 0;
        if (g < 90) {
          int kx = g / 18, ch = g - 18*kx;
          byte = (w2[(slot*18 + ch)*25 + ky*5 + kx] < 0.0f) ? 0xFFu : 0x01u;
        }
        d |= byte << (8*j);
      }
    }
    wsu[B2I + idx] = d;
  } else if (tid >= 7936 && tid < 12736) { // W3 packed [120][40]
    int idx = tid - 7936;
    int o = idx / 40, wj = idx - o*40;
    uint32_t b = 0;
    if (wj < 25) {
      int p = wj;
      for (int c = 0; c < 32; ++c)
        if (w3[(o*48 + c)*25 + p] < 0.0f) b |= 1u << c;
    } else if (wj < 38) {
      int j = wj - 25;
      int p0 = 2*j, p1 = 2*j + 1;
      for (int q = 0; q < 16; ++q) {
        int c = 32 + q;
        if (w3[(o*48 + c)*25 + p0] < 0.0f) b |= 1u << q;
        if (p1 < 25 && w3[(o*48 + c)*25 + p1] < 0.0f) b |= 1u << (16 + q);
      }
    }
    wsu[W3P + idx] = b;
  } else if (tid >= 12736 && tid < 12856) { // M3
    int o = tid - 12736;
    float S = bnS(g3[o], v3[o]);
    float B = cb3[o];
    float T = bnT(be3[o], m3[o], S);
    int M, iv; scanMT(B, S, T, 1200, M, iv);
    wsu[M3P + o] = (uint32_t)M | ((uint32_t)iv << 11);
  } else if (tid >= 12856 && tid < 13864) { // fw1 [o][4]
    int idx = tid - 12856;
    int o = idx >> 2, wi = idx & 3;
    uint32_t b = 0;
    for (int j = 0; j < 32; ++j) {
      int col = wi*32 + j;
      if (col < 120 && fw1[o*120 + col] < 0.0f) b |= 1u << j;
    }
    wsu[FW1P + idx] = b;
  } else if (tid >= 13864 && tid < 14116) { // M4
    int o = tid - 13864;
    float S = bnS(g4[o], v4[o]);
    float B = fb1[o];
    float T = bnT(be4[o], m4[o], S);
    int M, iv; scanMT(B, S, T, 120, M, iv);
    wsu[M4P + o] = (uint32_t)M | ((uint32_t)iv << 7);
  } else if (tid >= 14116 && tid < 14196) { // fw2 [wi*10+o]
    int i = tid - 14116;
    int wi = i / 10, o = i - wi*10;
    uint32_t b = 0;
    for (int j = 0; j < 32; ++j) {
      int col = wi*32 + j;
      if (col < 252 && fw2[o*252 + col] < 0.0f) b |= 1u << j;
    }
    wsu[FW2P + i] = b;
  }
}

__global__ __launch_bounds__(256, 6) void lenet_main(
    const float* __restrict__ x, const uint32_t* __restrict__ wsu,
    float* __restrict__ out)
{
  __shared__ __align__(16) uint8_t Alds[140*112];  // dense im2col rows [14][10][112B]
  __shared__ uint32_t xng[32], xnz[32];
  __shared__ __align__(16) uint32_t h2p[40];
  __shared__ uint32_t h3[4];
  __shared__ uint32_t h4[8];
  __shared__ int      sthr[48];
  __shared__ uint32_t lut[16];
  __shared__ int      znz[4];

  const int t = threadIdx.x;
  const int lane = t & 63, wv = t >> 6;
  const int img = blockIdx.x;

  // ---- input pack: t -> (row = t>>3, quad k = t&7), 4 px each ----
  {
    const float* xim = x + (size_t)img * 1024;
    const int row = t >> 3, k = t & 7;
    const float4 f = ((const float4*)(xim + row*32))[k];
    const uint32_t u0 = __float_as_uint(f.x), u1 = __float_as_uint(f.y),
                   u2 = __float_as_uint(f.z), u3 = __float_as_uint(f.w);
    uint32_t ng4 = (u0>>31) | ((u1>>31)<<1) | ((u2>>31)<<2) | ((u3>>31)<<3);
    uint32_t nz4 = (uint32_t)((u0<<1)!=0u) | ((uint32_t)((u1<<1)!=0u)<<1)
                 | ((uint32_t)((u2<<1)!=0u)<<2) | ((uint32_t)((u3<<1)!=0u)<<3);
    const bool tok = (nz4 == 0xFu);
    uint32_t ng = ng4 << (4*k), nz = nz4 << (4*k);
    ng |= __shfl_xor(ng, 1);  nz |= __shfl_xor(nz, 1);
    ng |= __shfl_xor(ng, 2);  nz |= __shfl_xor(nz, 2);
    ng |= __shfl_xor(ng, 4);  nz |= __shfl_xor(nz, 4);
    if (k == 0) { xng[row] = ng; xnz[row] = nz; }
    const int wok = __all(tok);
    if (lane == 0) znz[wv] = wok;
  }

  if (t < 16) {
    uint32_t v = 0;
    #pragma unroll
    for (int b = 0; b < 4; ++b) v |= (((t >> b) & 1) ? 0xFFu : 0x01u) << (8*b);
    lut[t] = v;
  }
  if (t < 40) h2p[t] = 0;
  if (t >= 64 && t < 112) sthr[t - 64] = (int)wsu[THRW + (t - 64)];
  __syncthreads();

  // ---- stage 1: conv1 + pool + threshold; fused dense im2col expand ----
  // thread map: row = t>>4 (0..13), px = t&15 (active px<14)
  const bool zer = !(znz[0] & znz[1] & znz[2] & znz[3]);
  {
    const int py = t >> 4, px = t & 15;
    const bool active = (py < 14) && (px < 14);
    uint32_t hm = 0;
    if (active) {
      const int x0 = 2*px, y0 = 2*py;
      if (!zer) {
        const uint32_t a0 = xng[y0+0] >> x0, a1 = xng[y0+1] >> x0,
                       a2 = xng[y0+2] >> x0, a3 = xng[y0+3] >> x0,
                       a4 = xng[y0+4] >> x0, a5 = xng[y0+5] >> x0;
        const uint32_t w00 = (a0&31u) | ((a1&31u)<<5) | ((a2&31u)<<10) | ((a3&31u)<<15) | ((a4&31u)<<20);
        const uint32_t w01 = ((a0>>1)&31u) | (((a1>>1)&31u)<<5) | (((a2>>1)&31u)<<10) | (((a3>>1)&31u)<<15) | (((a4>>1)&31u)<<20);
        const uint32_t w10 = (a1&31u) | ((a2&31u)<<5) | ((a3&31u)<<10) | ((a4&31u)<<15) | ((a5&31u)<<20);
        const uint32_t w11 = ((a1>>1)&31u) | (((a2>>1)&31u)<<5) | (((a3>>1)&31u)<<10) | (((a4>>1)&31u)<<15) | (((a5>>1)&31u)<<20);
        const uint32_t iv1 = wsu[INV1];
        #pragma unroll
        for (int c = 0; c < 18; ++c) {
          const uint32_t wd = wsu[W1P + c];
          const uint32_t wt = wd & 0x1FFFFFFu;
          const int M = (int)(wd >> 25);
          const int mn = min(min(__popc(w00^wt), __popc(w01^wt)),
                             min(__popc(w10^wt), __popc(w11^wt)));
          hm |= (mn >= M) ? (1u << c) : 0u;
        }
        hm ^= iv1;
      } else {                            // exact-zero-aware float path (rare)
        uint32_t an[6], az[6];
        #pragma unroll
        for (int r6 = 0; r6 < 6; ++r6) { an[r6] = xng[y0+r6] >> x0; az[r6] = xnz[y0+r6] >> x0; }
        for (int c = 0; c < 18; ++c) {
          const uint32_t wt = wsu[W1P + c] & 0x1FFFFFFu;
          const float B = __uint_as_float(wsu[CFP + c]);
          const float S = __uint_as_float(wsu[CFP + 18 + c]);
          const float T = __uint_as_float(wsu[CFP + 36 + c]);
          int best = -1000;
          #pragma unroll
          for (int dy = 0; dy < 2; ++dy)
            #pragma unroll
            for (int dx = 0; dx < 2; ++dx) {
              int cnt = 0, ng = 0;
              #pragma unroll
              for (int k = 0; k < 5; ++k) {
                const uint32_t nzr = (az[dy+k] >> dx) & 31u;
                const uint32_t sgr = (an[dy+k] >> dx) & 31u;
                const uint32_t wr  = (wt >> (5*k)) & 31u;
                cnt += __popc(nzr);
                ng  += __popc((sgr ^ wr) & nzr);
              }
              const int conv = cnt - 2*ng;
              best = best > conv ? best : conv;
            }
          if (negv(best, B, S, T)) hm |= 1u << c;
        }
      }
    }
    // gather masks of pixels px..px+4 (same 16-lane row group -> in-wave shfl)
    const uint32_t m0 = hm;
    const uint32_t m1 = __shfl_down(hm, 1);
    const uint32_t m2 = __shfl_down(hm, 2);
    const uint32_t m3 = __shfl_down(hm, 3);
    const uint32_t m4 = __shfl_down(hm, 4);
    if (py < 14 && px < 10) {
      // expand each 18-bit mask to 18 bytes; pack at byte offsets 0,18,36,54,72
      uint32_t e0[5], e1[5], e2[5], e3[5], e4[5];
      const uint32_t mm[5] = {m0, m1, m2, m3, m4};
      #pragma unroll
      for (int k = 0; k < 5; ++k) {
        e0[k] = lut[mm[k] & 15u];
        e1[k] = lut[(mm[k] >> 4) & 15u];
        e2[k] = lut[(mm[k] >> 8) & 15u];
        e3[k] = lut[(mm[k] >> 12) & 15u];
        e4[k] = lut[(mm[k] >> 16) & 15u] & 0xFFFFu;
      }
      uint32_t w[24];
      w[0]=e0[0]; w[1]=e1[0]; w[2]=e2[0]; w[3]=e3[0];
      w[4]  = e4[0] | (e0[1] << 16);
      w[5]  = (e0[1] >> 16) | (e1[1] << 16);
      w[6]  = (e1[1] >> 16) | (e2[1] << 16);
      w[7]  = (e2[1] >> 16) | (e3[1] << 16);
      w[8]  = (e3[1] >> 16) | (e4[1] << 16);
      w[9]=e0[2]; w[10]=e1[2]; w[11]=e2[2]; w[12]=e3[2];
      w[13] = e4[2] | (e0[3] << 16);
      w[14] = (e0[3] >> 16) | (e1[3] << 16);
      w[15] = (e1[3] >> 16) | (e2[3] << 16);
      w[16] = (e2[3] >> 16) | (e3[3] << 16);
      w[17] = (e3[3] >> 16) | (e4[3] << 16);
      w[18]=e0[4]; w[19]=e1[4]; w[20]=e2[4]; w[21]=e3[4];
      w[22] = e4[4];
      w[23] = 0;
      uint8_t* ap = Alds + (py*10 + px)*112;
      #pragma unroll
      for (int q = 0; q < 6; ++q)
        *(uint4*)(ap + q*16) = make_uint4(w[4*q], w[4*q+1], w[4*q+2], w[4*q+3]);
    }
  }
  __syncthreads();

  // ---- stage 2: conv2 as i8 MFMA, dense K=480 (15 slices) ----
  {
    const int rl = lane & 31, kh = lane >> 5;
    const int q   = (wv << 3) + (rl >> 2);
    const int qc  = q < 24 ? q : 24;           // clamp for in-bounds addresses
    const int wnd = rl & 3;
    const int py = qc / 5, px = qc - py*5;
    const int Y0 = 2*py + (wnd >> 1), X0 = 2*px + (wnd & 1);
    const uint8_t* abase = Alds + (Y0*10 + X0)*112 + (kh << 4);
    const uint8_t* bg = (const uint8_t*)(wsu + B2I) + (rl*32 + kh*16);

    v16i acc0 = {};
    v16i acc1 = {};
    #pragma unroll
    for (int s = 0; s < 15; ++s) {
      const int ky = s / 3, part = s - 3*(s/3);
      v4i a  = *(const v4i*)(abase + ky*1120 + part*32);
      v4i b0 = *(const v4i*)(bg + s*2048);
      v4i b1 = *(const v4i*)(bg + s*2048 + 1024);
      acc0 = __builtin_amdgcn_mfma_i32_32x32x32_i8(a, b0, acc0, 0, 0, 0);
      acc1 = __builtin_amdgcn_mfma_i32_32x32x32_i8(a, b1, acc1, 0, 0, 0);
    }

    const int D0 = sthr[rl];
    const int D1 = sthr[rl + 32 < 47 ? rl + 32 : 47];
    const uint32_t ivm0 = wsu[INVM];
    const uint32_t ivm1d = (wsu[INVM + 1] & 0xFFFFu) * 0x10001u;
    #pragma unroll
    for (int g = 0; g < 4; ++g) {
      const int p0 = max(max(acc0[4*g], acc0[4*g+1]), max(acc0[4*g+2], acc0[4*g+3]));
      const int p1 = max(max(acc1[4*g], acc1[4*g+1]), max(acc1[4*g+2], acc1[4*g+3]));
      unsigned long long e0 = __ballot(p0 <= D0);
      unsigned long long e1 = __ballot(p1 <= D1);
      if (lane == 0) {
        const int pool = (wv << 3) + 2*g;
        if (pool < 25) {
          h2p[pool] = (uint32_t)e0 ^ ivm0;
          uint32_t hw = ((uint32_t)e1 & 0xFFFFu) | (((uint32_t)(e1 >> 32) & 0xFFFFu) << 16);
          hw ^= ivm1d;
          if (pool + 1 < 25) h2p[pool + 1] = (uint32_t)(e0 >> 32) ^ ivm0;
          else hw &= 0xFFFFu;
          h2p[25 + (pool >> 1)] = hw;
        }
      }
    }
  }
  __syncthreads();

  // ---- stage 3: conv3 (48->120), 240 thr = (o, half), shfl combine ----
  {
    bool pred = false;
    if (t < 240) {
      const int o = t >> 1, h = t & 1;
      const uint4* wp = (const uint4*)(wsu + W3P + o*40 + h*20);
      const uint32_t* hv = &h2p[h*20];
      int mm = 0;
      #pragma unroll
      for (int qq = 0; qq < 5; ++qq) {
        const uint4 ww = wp[qq];
        mm += __popc(hv[qq*4+0] ^ ww.x) + __popc(hv[qq*4+1] ^ ww.y)
            + __popc(hv[qq*4+2] ^ ww.z) + __popc(hv[qq*4+3] ^ ww.w);
      }
      mm += __shfl_xor(mm, 1);
      const uint32_t mw = wsu[M3P + o];
      pred = (((mm >= (int)(mw & 2047u)) ? 1u : 0u) ^ (mw >> 11)) != 0u;
    }
    unsigned long long bb = __ballot(pred && ((t & 1) == 0));
    unsigned long long xq = bb & 0x5555555555555555ull;
    xq = (xq | (xq >> 1))  & 0x3333333333333333ull;
    xq = (xq | (xq >> 2))  & 0x0F0F0F0F0F0F0F0Full;
    xq = (xq | (xq >> 4))  & 0x00FF00FF00FF00FFull;
    xq = (xq | (xq >> 8))  & 0x0000FFFF0000FFFFull;
    xq = (xq | (xq >> 16)) & 0x00000000FFFFFFFFull;
    if (lane == 0) h3[wv] = (uint32_t)xq;
  }
  __syncthreads();

  // ---- stage 4: fc1 (120->252), ballot -> h4 bits (252 threads) ----
  {
    bool pred = false;
    if (t < 252) {
      const uint4 fr = ((const uint4*)(wsu + FW1P))[t];
      const int mm = __popc(h3[0] ^ fr.x) + __popc(h3[1] ^ fr.y)
                   + __popc(h3[2] ^ fr.z) + __popc(h3[3] ^ fr.w);
      const uint32_t mw = wsu[M4P + t];
      pred = (((mm >= (int)(mw & 127u)) ? 1u : 0u) ^ (mw >> 7)) != 0u;
    }
    unsigned long long bb = __ballot(pred);
    if (lane == 0) {
      h4[wv*2]   = (uint32_t)bb;
      h4[wv*2+1] = (uint32_t)(bb >> 32);
    }
  }
  __syncthreads();

  // ---- stage 5: fc2 + bn + log_softmax (16 lanes) ----
  if (t < 16) {
    float vv = -1e30f;
    if (t < 10) {
      int mm = 0;
      #pragma unroll
      for (int wi = 0; wi < 8; ++wi)
        mm += __popc(h4[wi] ^ wsu[FW2P + wi*10 + t]);
      const int dot = 252 - 2*mm;
      const float B = __uint_as_float(wsu[CFP + 54 + t]);
      const float S = __uint_as_float(wsu[CFP + 64 + t]);
      const float T = __uint_as_float(wsu[CFP + 74 + t]);
      float v = __fadd_rn((float)dot, B);
      v = __fmul_rn(v, S);
      vv = __fadd_rn(v, T);
    }
    float mx = vv;
    #pragma unroll
    for (int d = 1; d < 16; d <<= 1)
      mx = fmaxf(mx, __shfl_xor(mx, d, 16));
    const float sh = __fsub_rn(vv, mx);
    float s = expf(sh);
    #pragma unroll
    for (int d = 1; d < 16; d <<= 1)
      s = __fadd_rn(s, __shfl_xor(s, d, 16));
    if (t < 10)
      out[(size_t)img*10 + t] = __fsub_rn(sh, logf(s));
  }
}

extern "C" void kernel_launch(void* const* d_in, const int* in_sizes, int n_in,
                              void* d_out, int out_size, void* d_ws, size_t ws_size,
                              hipStream_t stream)
{
  const float* x   = (const float*)d_in[0];
  const float* w1  = (const float*)d_in[1];
  const float* cb1 = (const float*)d_in[2];
  const float* g1  = (const float*)d_in[3];
  const float* be1 = (const float*)d_in[4];
  const float* m1  = (const float*)d_in[5];
  const float* v1  = (const float*)d_in[6];
  const float* w2  = (const float*)d_in[7];
  const float* cb2 = (const float*)d_in[8];
  const float* g2  = (const float*)d_in[9];
  const float* be2 = (const float*)d_in[10];
  const float* m2  = (const float*)d_in[11];
  const float* v2  = (const float*)d_in[12];
  const float* w3  = (const float*)d_in[13];
  const float* cb3 = (const float*)d_in[14];
  const float* g3  = (const float*)d_in[15];
  const float* be3 = (const float*)d_in[16];
  const float* m3  = (const float*)d_in[17];
  const float* v3  = (const float*)d_in[18];
  const float* fw1 = (const float*)d_in[19];
  const float* fb1 = (const float*)d_in[20];
  const float* g4  = (const float*)d_in[21];
  const float* be4 = (const float*)d_in[22];
  const float* m4  = (const float*)d_in[23];
  const float* v4  = (const float*)d_in[24];
  const float* fw2 = (const float*)d_in[25];
  const float* fb2 = (const float*)d_in[26];
  const float* g5  = (const float*)d_in[27];
  const float* be5 = (const float*)d_in[28];
  const float* m5  = (const float*)d_in[29];
  const float* v5  = (const float*)d_in[30];

  uint32_t* wsu = (uint32_t*)d_ws;
  float* out = (float*)d_out;

  hipLaunchKernelGGL(pack_kernel, dim3(56), dim3(256), 0, stream,
                     w1, w2, w3, fw1, fw2,
                     cb1, g1, be1, m1, v1,
                     cb2, g2, be2, m2, v2,
                     cb3, g3, be3, m3, v3,
                     fb1, g4, be4, m4, v4,
                     fb2, g5, be5, m5, v5,
                     wsu);

  hipLaunchKernelGGL(lenet_main, dim3(4096), dim3(256), 0, stream,
                     x, wsu, out);
}